// Round 5
// baseline (1174.251 us; speedup 1.0000x reference)
//
#include <hip/hip_runtime.h>
#include <hip/hip_fp16.h>
#include <string.h>

#define PER  149796
#define NN   1048573          // 1 + 7*PER
#define HDIM 64
#define EDIM 32
#define NIOU 192

typedef _Float16 f16;
typedef _Float16 f16x8 __attribute__((ext_vector_type(8)));
typedef _Float16 f16x2 __attribute__((ext_vector_type(2)));
typedef float    f32x4 __attribute__((ext_vector_type(4)));

__device__ __forceinline__ float sigf(float x){ return 1.0f/(1.0f+__expf(-x)); }
__device__ __forceinline__ float tanh_f(float x){
  float ax = fabsf(x);
  float e  = __expf(-2.0f*ax);
  float t  = (1.0f - e)/(1.0f + e);
  return x < 0.0f ? -t : t;
}

// packed f16x2 global atomic add (fire-and-forget).
__device__ __forceinline__ void atomAddH2(f16x2* p, f16 a, f16 b){
#if defined(__HIP_DEVICE_COMPILE__)
  typedef _Float16 h2 __attribute__((ext_vector_type(2)));
  h2 v; v[0]=a; v[1]=b;
  (void)__builtin_amdgcn_global_atomic_fadd_v2f16(
      (__attribute__((address_space(1))) h2*)p, v);
#else
  (void)p; (void)a; (void)b;
#endif
}

// ================= tables + MFMA packs (fused) =================
// packIOU[v][col] = float4{ (Wiou.x)[col]+b, (Wiou.x)[64+col]+b, (Wiou.x)[128+col]+b, 0 }
// -> one 16B gather replaces three strided 4B gathers in the level epilogue.
// B-frag order for mfma_f32_16x16x32_f16 (verified R4): lane L: n=t*16+(L&15), k=s*32+(L>>4)*8+j
__global__ __launch_bounds__(256) void tablepack_kernel(
    const float* __restrict__ emb, const float* __restrict__ Wiou, const float* __restrict__ biou,
    const float* __restrict__ Wf, const float* __restrict__ bf,
    const float* __restrict__ Uf, const float* __restrict__ Uiou,
    f32x4* __restrict__ packIOU, float* __restrict__ embWf,
    f16* __restrict__ Bfp, f16* __restrict__ Biop)
{
  if (blockIdx.x < 1024){
    int v = blockIdx.x;
    int m = threadIdx.x;
    const float* x = emb + (size_t)v*EDIM;
    if (m < HDIM){
      float a = biou[m], b = biou[HDIM+m], c = biou[2*HDIM+m];
      #pragma unroll
      for (int e=0;e<EDIM;e++){
        float xe = x[e];
        a += Wiou[(size_t)m*EDIM+e]*xe;
        b += Wiou[(size_t)(HDIM+m)*EDIM+e]*xe;
        c += Wiou[(size_t)(2*HDIM+m)*EDIM+e]*xe;
      }
      f32x4 o; o.x=a; o.y=b; o.z=c; o.w=0.f;
      packIOU[(size_t)v*HDIM + m] = o;
    } else if (m < 2*HDIM){
      int mm = m - HDIM;
      float a = bf[mm];
      #pragma unroll
      for (int e=0;e<EDIM;e++) a += Wf[(size_t)mm*EDIM+e]*x[e];
      embWf[(size_t)v*HDIM + mm] = a;
    }
  } else {
    for (int i = threadIdx.x; i < 2*4*64*8; i += 256){
      int j = i & 7, L = (i>>3)&63, st = i>>9;
      int t = st & 3, s = st >> 2;
      int k = s*32 + (L>>4)*8 + j;
      int n = t*16 + (L&15);
      Bfp[i] = (f16)Uf[n*HDIM + k];
    }
    for (int i = threadIdx.x; i < 2*12*64*8; i += 256){
      int j = i & 7, L = (i>>3)&63, st = i>>9;
      int t = st % 12, s = st / 12;
      int k = s*32 + (L>>4)*8 + j;
      int n = t*16 + (L&15);
      Biop[i] = (f16)Uiou[n*HDIM + k];
    }
  }
}

// ================= per-level kernel (push design, no CSR) =================
// 256 threads = 4 independent waves; each wave owns 16 nodes (R1 structure,
// verified 56.5us/level). Barriers kept: they phase the memory streams so the
// atomic-target buffer stays cache-resident (removing them was a 2.5x loss).
// mode: 0 = leaf (no accum read, atomic out)
//       1 = mid  (accum read, atomic out)
//       2 = level1 (accum read, plain contiguous out)
// zin: 1 -> zero own accIn rows after reading (they become accOut at the
//      next level), replacing a separate 38MB memset dispatch.
__global__ __launch_bounds__(256,8) void level_kernel(
    const int* __restrict__ tok, const int* __restrict__ parent,
    const f32x4* __restrict__ packIOU, const float* __restrict__ embWf,
    const f16* __restrict__ Biopack, const f16* __restrict__ Ufpack,
    const f16x2* __restrict__ accIn, f16x2* __restrict__ accOut,
    int poff, int ppoff, int mode, int zin)
{
  __shared__ f16 Ah[4][16*72];     // 4 x 2304 B
  __shared__ f16 FAf[4][16*68];    // 4 x 2176 B
  int lane = threadIdx.x & 63;
  int w    = threadIdx.x >> 6;
  int j0   = (blockIdx.x*4 + w)*16;
  int q = lane>>4, c16 = lane&15;
  f16* AhW  = &Ah[w][0];
  f16* FAfW = &FAf[w][0];

  // ---- phase 1: own accumulated child-sums (contiguous) -> LDS transpose
  if (mode != 0){
    #pragma unroll
    for (int i=0;i<16;i++){
      int j = j0 + i; if (j > PER-1) j = PER-1;
      f16x2 v = accIn[(size_t)j*HDIM + lane];
      AhW[i*72 + lane]  = v.x;
      FAfW[i*68 + lane] = v.y;
    }
  } else {
    #pragma unroll
    for (int i=0;i<16;i++){
      AhW[i*72 + lane]  = (f16)0.f;
      FAfW[i*68 + lane] = (f16)0.f;
    }
  }
  __syncthreads();
  f16x8 A0 = *(const f16x8*)(AhW + c16*72 + q*8);
  f16x8 A1 = *(const f16x8*)(AhW + c16*72 + 32 + q*8);

  // zero own accIn rows for reuse as the atomic target at the next level.
  if (mode != 0 && zin){
    f16x2 z; z.x = (f16)0.f; z.y = (f16)0.f;
    #pragma unroll
    for (int i=0;i<16;i++){
      int j = j0 + i;
      if (j < PER) ((f16x2*)accIn)[(size_t)j*HDIM + lane] = z;
    }
  }

  // ---- phase 2: iou MFMA + epilogue
  const f16x8* Bp = (const f16x8*)Biopack;
  f32x4 acc[12];
  #pragma unroll
  for (int nt=0;nt<12;nt++) acc[nt] = (f32x4){0.f,0.f,0.f,0.f};
  #pragma unroll
  for (int nt=0;nt<12;nt++){
    f16x8 B0 = Bp[nt*64 + lane];
    f16x8 B1 = Bp[(12+nt)*64 + lane];
    acc[nt] = __builtin_amdgcn_mfma_f32_16x16x32_f16(A0, B0, acc[nt], 0,0,0);
    acc[nt] = __builtin_amdgcn_mfma_f32_16x16x32_f16(A1, B1, acc[nt], 0,0,0);
  }
  float cc[4][4];
  f16   hh[4][4];
  int   prow_[4]; int wt_[4]; bool ok_[4];
  #pragma unroll
  for (int r=0;r<4;r++){
    int j = j0 + q*4 + r;
    bool ok = j < PER;
    int jl = ok ? j : PER-1;
    int g = poff + jl;
    int tk = tok[g];
    const f32x4* tr = packIOU + (size_t)tk*HDIM;
    ok_[r] = ok;
    if (mode != 2){
      int pg = parent[g];
      prow_[r] = pg - ppoff;          // parent's level-local row
      wt_[r]   = tok[pg];             // parent's token for Uf part
    } else {
      prow_[r] = jl;                  // own row (contiguous write)
      wt_[r]   = tok[0];              // root token
    }
    int prow = q*4 + r;
    #pragma unroll
    for (int nt=0;nt<4;nt++){
      int col = nt*16 + c16;
      f32x4 wx = tr[col];             // one 16B gather: {i,o,u,_}
      float ai = acc[nt][r]   + wx.x;
      float ao = acc[nt+4][r] + wx.y;
      float au = acc[nt+8][r] + wx.z;
      float fav = (float)FAfW[prow*68 + col];
      float c = sigf(ai)*tanh_f(au) + fav;
      float h = sigf(ao)*tanh_f(c);
      cc[r][nt] = c;
      hh[r][nt] = (f16)h;
    }
  }
  __syncthreads();
  // ---- phase 3: h -> Ah (A-layout), Uf MFMA, push {h,fc}
  #pragma unroll
  for (int r=0;r<4;r++)
    #pragma unroll
    for (int nt=0;nt<4;nt++)
      AhW[(q*4+r)*72 + nt*16 + c16] = hh[r][nt];
  __syncthreads();
  f16x8 H0 = *(const f16x8*)(AhW + c16*72 + q*8);
  f16x8 H1 = *(const f16x8*)(AhW + c16*72 + 32 + q*8);
  const f16x8* Up = (const f16x8*)Ufpack;
  f32x4 g4[4];
  #pragma unroll
  for (int nt=0;nt<4;nt++) g4[nt] = (f32x4){0.f,0.f,0.f,0.f};
  #pragma unroll
  for (int nt=0;nt<4;nt++){
    f16x8 B0 = Up[nt*64 + lane];
    f16x8 B1 = Up[(4+nt)*64 + lane];
    g4[nt] = __builtin_amdgcn_mfma_f32_16x16x32_f16(H0, B0, g4[nt], 0,0,0);
    g4[nt] = __builtin_amdgcn_mfma_f32_16x16x32_f16(H1, B1, g4[nt], 0,0,0);
  }
  #pragma unroll
  for (int r=0;r<4;r++){
    if (!ok_[r]) continue;
    const float* wr = embWf + (size_t)wt_[r]*HDIM;
    size_t rb = (size_t)prow_[r]*HDIM;
    #pragma unroll
    for (int nt=0;nt<4;nt++){
      int col = nt*16 + c16;
      float v = sigf(g4[nt][r] + wr[col]) * cc[r][nt];
      if (mode == 2){
        f16x2 o; o.x = hh[r][nt]; o.y = (f16)v;
        accOut[rb + col] = o;
      } else {
        atomAddH2(&accOut[rb + col], hh[r][nt], (f16)v);
      }
    }
  }
}

// ================= root =================
__global__ __launch_bounds__(256) void rootred_kernel(
    const f16x2* __restrict__ HFin, float* __restrict__ rootacc)
{
  int t = blockIdx.x*blockDim.x + threadIdx.x;
  int m = t & 63;
  int j0 = t >> 6;
  int jstep = (gridDim.x*blockDim.x) >> 6;
  float af=0.f, ah=0.f;
  for (int j=j0; j<PER; j+=jstep){
    f16x2 v = HFin[(size_t)j*HDIM + m];
    ah += (float)v.x;
    af += (float)v.y;
  }
  __shared__ float red[256];
  red[threadIdx.x]=af; __syncthreads();
  if (threadIdx.x < 64) atomicAdd(&rootacc[m],    red[m]+red[64+m]+red[128+m]+red[192+m]);
  __syncthreads();
  red[threadIdx.x]=ah; __syncthreads();
  if (threadIdx.x < 64) atomicAdd(&rootacc[64+m], red[m]+red[64+m]+red[128+m]+red[192+m]);
}

__global__ void rootnode_kernel(
    const int* __restrict__ tok, const float* __restrict__ emb,
    const float* __restrict__ Wiou, const float* __restrict__ biou, const float* __restrict__ Uiou,
    const float* __restrict__ rootacc, float* __restrict__ out)
{
  int m = threadIdx.x;
  if (m >= HDIM) return;
  int t = tok[0];
  float ai=biou[m], ao=biou[HDIM+m], au=biou[2*HDIM+m];
  for (int e=0;e<EDIM;e++){
    float xe = emb[(size_t)t*EDIM+e];
    ai += Wiou[(size_t)m*EDIM+e]*xe;
    ao += Wiou[(size_t)(HDIM+m)*EDIM+e]*xe;
    au += Wiou[(size_t)(2*HDIM+m)*EDIM+e]*xe;
  }
  for (int k=0;k<HDIM;k++){
    float hv = rootacc[64+k];
    ai += Uiou[(size_t)m*HDIM+k]*hv;
    ao += Uiou[(size_t)(HDIM+m)*HDIM+k]*hv;
    au += Uiou[(size_t)(2*HDIM+m)*HDIM+k]*hv;
  }
  float c = sigf(ai)*tanh_f(au) + rootacc[m];
  out[m] = sigf(ao)*tanh_f(c);
}

// ================= launch =================
static inline char* alignup(char* p){
  uintptr_t u = (uintptr_t)p;
  u = (u + 255) & ~(uintptr_t)255;
  return (char*)u;
}

extern "C" void kernel_launch(void* const* d_in, const int* in_sizes, int n_in,
                              void* d_out, int out_size, void* d_ws, size_t ws_size,
                              hipStream_t stream)
{
  const int*   tok    = (const int*)d_in[0];
  const int*   parent = (const int*)d_in[1];
  const float* emb    = (const float*)d_in[4];
  const float* Wiou   = (const float*)d_in[5];
  const float* biou   = (const float*)d_in[6];
  const float* Uiou   = (const float*)d_in[7];
  const float* Wf     = (const float*)d_in[8];
  const float* bf     = (const float*)d_in[9];
  const float* Uf     = (const float*)d_in[10];
  float* out = (float*)d_out;

  char* w = (char*)d_ws;
  size_t BUF = (size_t)PER*HDIM*sizeof(f16x2);     // 38.3 MB
  f16x2* bufA    = (f16x2*)w;  w = alignup(w + BUF);
  f16x2* bufB    = (f16x2*)w;  w = alignup(w + BUF);
  f32x4* packIOU = (f32x4*)w;  w = alignup(w + (size_t)1024*HDIM*sizeof(f32x4));
  float* embWf   = (float*)w;  w = alignup(w + 1024*HDIM*sizeof(float));
  float* rootacc = (float*)w;  w = alignup(w + 128*sizeof(float));
  f16*   Ufpack  = (f16*)w;    w = alignup(w + 2*4*64*8*sizeof(f16));
  f16*   Biopack = (f16*)w;    w = alignup(w + 2*12*64*8*sizeof(f16));

  const int NB = (PER + 63)/64;   // 2341 blocks of 256 threads (4 waves x 16 nodes)

  (void)hipMemsetAsync(rootacc, 0, 128*sizeof(float), stream);
  (void)hipMemsetAsync(bufA, 0, BUF, stream);
  (void)hipMemsetAsync(bufB, 0, BUF, stream);
  tablepack_kernel<<<1025, 256, 0, stream>>>(emb, Wiou, biou, Wf, bf, Uf, Uiou,
                                             packIOU, embWf, Ufpack, Biopack);

  // level d kernel: nodes at poff=1+(d-1)*PER; parents at ppoff=1+(d-2)*PER
  // d=7 (leaves): mode 0 -> atomic into bufA (accum for level 6)
  // d=6..2:       mode 1 -> read own accum, atomic into other buf
  //               zin=1 for d>=3: zero accIn in-kernel (it is the atomic
  //               target at the next level) instead of a memset dispatch.
  // d=1:          mode 2 -> read own accum, plain write {h,fc} (for rootred)
  f16x2* accIn  = nullptr;
  f16x2* accOut = bufA;
  level_kernel<<<NB, 256, 0, stream>>>(tok, parent, packIOU, embWf, Biopack, Ufpack,
                                       nullptr, bufA, 1 + 6*PER, 1 + 5*PER, 0, 0);
  accIn = bufA; accOut = bufB;
  for (int d=6; d>=2; --d){
    level_kernel<<<NB, 256, 0, stream>>>(tok, parent, packIOU, embWf, Biopack, Ufpack,
                                         accIn, accOut, 1 + (d-1)*PER, 1 + (d-2)*PER, 1,
                                         (d >= 3) ? 1 : 0);
    f16x2* t2 = accIn; accIn = accOut; accOut = t2;
  }
  // d=1: plain contiguous write into accOut (full overwrite, no zero needed)
  level_kernel<<<NB, 256, 0, stream>>>(tok, parent, packIOU, embWf, Biopack, Ufpack,
                                       accIn, accOut, 1, 0, 2, 0);

  rootred_kernel<<<256, 256, 0, stream>>>(accOut, rootacc);
  rootnode_kernel<<<1, 64, 0, stream>>>(tok, emb, Wiou, biou, Uiou, rootacc, out);
}

// Round 6
// 1000.631 us; speedup vs baseline: 1.1735x; 1.1735x over previous
//
#include <hip/hip_runtime.h>
#include <hip/hip_fp16.h>
#include <string.h>

#define PER  149796
#define NN   1048573          // 1 + 7*PER
#define HDIM 64
#define EDIM 32
#define NIOU 192

typedef _Float16 f16;
typedef _Float16 f16x8 __attribute__((ext_vector_type(8)));
typedef _Float16 f16x2 __attribute__((ext_vector_type(2)));
typedef float    f32x4 __attribute__((ext_vector_type(4)));

__device__ __forceinline__ float sigf(float x){ return 1.0f/(1.0f+__expf(-x)); }
__device__ __forceinline__ float tanh_f(float x){
  float ax = fabsf(x);
  float e  = __expf(-2.0f*ax);
  float t  = (1.0f - e)/(1.0f + e);
  return x < 0.0f ? -t : t;
}

// packed f16x2 global atomic add (fire-and-forget).
__device__ __forceinline__ void atomAddH2(f16x2* p, f16 a, f16 b){
#if defined(__HIP_DEVICE_COMPILE__)
  typedef _Float16 h2 __attribute__((ext_vector_type(2)));
  h2 v; v[0]=a; v[1]=b;
  (void)__builtin_amdgcn_global_atomic_fadd_v2f16(
      (__attribute__((address_space(1))) h2*)p, v);
#else
  (void)p; (void)a; (void)b;
#endif
}

// ================= tables + MFMA packs (fused) =================
// B-frag order for mfma_f32_16x16x32_f16 (verified R4): lane L: n=t*16+(L&15), k=s*32+(L>>4)*8+j
__global__ __launch_bounds__(256) void tablepack_kernel(
    const float* __restrict__ emb, const float* __restrict__ Wiou, const float* __restrict__ biou,
    const float* __restrict__ Wf, const float* __restrict__ bf,
    const float* __restrict__ Uf, const float* __restrict__ Uiou,
    float* __restrict__ embWiou, float* __restrict__ embWf,
    f16* __restrict__ Bfp, f16* __restrict__ Biop)
{
  if (blockIdx.x < 1024){
    int v = blockIdx.x;
    int m = threadIdx.x;
    const float* x = emb + (size_t)v*EDIM;
    if (m < NIOU){
      float a = biou[m];
      #pragma unroll
      for (int e=0;e<EDIM;e++) a += Wiou[m*EDIM+e]*x[e];
      embWiou[(size_t)v*NIOU + m] = a;
    } else {
      int mm = m - NIOU;
      float a = bf[mm];
      #pragma unroll
      for (int e=0;e<EDIM;e++) a += Wf[mm*EDIM+e]*x[e];
      embWf[(size_t)v*HDIM + mm] = a;
    }
  } else {
    for (int i = threadIdx.x; i < 2*4*64*8; i += 256){
      int j = i & 7, L = (i>>3)&63, st = i>>9;
      int t = st & 3, s = st >> 2;
      int k = s*32 + (L>>4)*8 + j;
      int n = t*16 + (L&15);
      Bfp[i] = (f16)Uf[n*HDIM + k];
    }
    for (int i = threadIdx.x; i < 2*12*64*8; i += 256){
      int j = i & 7, L = (i>>3)&63, st = i>>9;
      int t = st % 12, s = st / 12;
      int k = s*32 + (L>>4)*8 + j;
      int n = t*16 + (L&15);
      Biop[i] = (f16)Uiou[n*HDIM + k];
    }
  }
}

// ================= per-level kernel (push design, no CSR) =================
// 256 threads = 4 independent waves; each wave owns 16 nodes (as the old
// 64-thread block did). Single-wave workgroups cap at ~16 WG/CU (occupancy
// was 35%); 4-wave blocks with VGPR<=64 allow 8 blocks/CU = 32 waves (100%).
// mode: 0 = leaf (no accum read, atomic out)
//       1 = mid  (accum read, atomic out)
//       2 = level1 (accum read, plain contiguous out)
// zin: 1 -> zero own accIn rows after reading (they become accOut at the
//      next level), replacing a separate 38MB memset dispatch.
__global__ __launch_bounds__(256,8) void level_kernel(
    const int* __restrict__ tok, const int* __restrict__ parent,
    const float* __restrict__ embWiou, const float* __restrict__ embWf,
    const f16* __restrict__ Biopack, const f16* __restrict__ Ufpack,
    const f16x2* __restrict__ accIn, f16x2* __restrict__ accOut,
    int poff, int ppoff, int mode, int zin)
{
  __shared__ f16 Ah[4][16*72];     // 4 x 2304 B
  __shared__ f16 FAf[4][16*68];    // 4 x 2176 B
  int lane = threadIdx.x & 63;
  int w    = threadIdx.x >> 6;
  int j0   = (blockIdx.x*4 + w)*16;
  int q = lane>>4, c16 = lane&15;
  f16* AhW  = &Ah[w][0];
  f16* FAfW = &FAf[w][0];

  // ---- phase 1: own accumulated child-sums (contiguous) -> LDS transpose
  if (mode != 0){
    #pragma unroll
    for (int i=0;i<16;i++){
      int j = j0 + i; if (j > PER-1) j = PER-1;
      f16x2 v = accIn[(size_t)j*HDIM + lane];
      AhW[i*72 + lane]  = v.x;
      FAfW[i*68 + lane] = v.y;
    }
  } else {
    #pragma unroll
    for (int i=0;i<16;i++){
      AhW[i*72 + lane]  = (f16)0.f;
      FAfW[i*68 + lane] = (f16)0.f;
    }
  }
  __syncthreads();
  f16x8 A0 = *(const f16x8*)(AhW + c16*72 + q*8);
  f16x8 A1 = *(const f16x8*)(AhW + c16*72 + 32 + q*8);

  // zero own accIn rows for reuse as the atomic target at the next level.
  // (reads above already consumed; stores drain under the MFMA phase.
  //  clamped duplicate rows (j>=PER) are only read by lanes whose outputs
  //  are discarded, so the read/zero race there is benign.)
  if (mode != 0 && zin){
    f16x2 z; z.x = (f16)0.f; z.y = (f16)0.f;
    #pragma unroll
    for (int i=0;i<16;i++){
      int j = j0 + i;
      if (j < PER) ((f16x2*)accIn)[(size_t)j*HDIM + lane] = z;
    }
  }

  // ---- phase 2: iou MFMA + epilogue
  const f16x8* Bp = (const f16x8*)Biopack;
  f32x4 acc[12];
  #pragma unroll
  for (int nt=0;nt<12;nt++) acc[nt] = (f32x4){0.f,0.f,0.f,0.f};
  #pragma unroll
  for (int nt=0;nt<12;nt++){
    f16x8 B0 = Bp[nt*64 + lane];
    f16x8 B1 = Bp[(12+nt)*64 + lane];
    acc[nt] = __builtin_amdgcn_mfma_f32_16x16x32_f16(A0, B0, acc[nt], 0,0,0);
    acc[nt] = __builtin_amdgcn_mfma_f32_16x16x32_f16(A1, B1, acc[nt], 0,0,0);
  }
  float cc[4][4];
  f16   hh[4][4];
  int   prow_[4]; int wt_[4]; bool ok_[4];
  #pragma unroll
  for (int r=0;r<4;r++){
    int j = j0 + q*4 + r;
    bool ok = j < PER;
    int jl = ok ? j : PER-1;
    int g = poff + jl;
    int tk = tok[g];
    const float* tr = embWiou + (size_t)tk*NIOU;
    ok_[r] = ok;
    if (mode != 2){
      int pg = parent[g];
      prow_[r] = pg - ppoff;          // parent's level-local row
      wt_[r]   = tok[pg];             // parent's token for Uf part
    } else {
      prow_[r] = jl;                  // own row (contiguous write)
      wt_[r]   = tok[0];              // root token
    }
    int prow = q*4 + r;
    #pragma unroll
    for (int nt=0;nt<4;nt++){
      int col = nt*16 + c16;
      float ai = acc[nt][r]   + tr[col];
      float ao = acc[nt+4][r] + tr[64+col];
      float au = acc[nt+8][r] + tr[128+col];
      float fav = (float)FAfW[prow*68 + col];
      float c = sigf(ai)*tanh_f(au) + fav;
      float h = sigf(ao)*tanh_f(c);
      cc[r][nt] = c;
      hh[r][nt] = (f16)h;
    }
  }
  __syncthreads();
  // ---- phase 3: h -> Ah (A-layout), Uf MFMA, push {h,fc}
  #pragma unroll
  for (int r=0;r<4;r++)
    #pragma unroll
    for (int nt=0;nt<4;nt++)
      AhW[(q*4+r)*72 + nt*16 + c16] = hh[r][nt];
  __syncthreads();
  f16x8 H0 = *(const f16x8*)(AhW + c16*72 + q*8);
  f16x8 H1 = *(const f16x8*)(AhW + c16*72 + 32 + q*8);
  const f16x8* Up = (const f16x8*)Ufpack;
  f32x4 g4[4];
  #pragma unroll
  for (int nt=0;nt<4;nt++) g4[nt] = (f32x4){0.f,0.f,0.f,0.f};
  #pragma unroll
  for (int nt=0;nt<4;nt++){
    f16x8 B0 = Up[nt*64 + lane];
    f16x8 B1 = Up[(4+nt)*64 + lane];
    g4[nt] = __builtin_amdgcn_mfma_f32_16x16x32_f16(H0, B0, g4[nt], 0,0,0);
    g4[nt] = __builtin_amdgcn_mfma_f32_16x16x32_f16(H1, B1, g4[nt], 0,0,0);
  }
  #pragma unroll
  for (int r=0;r<4;r++){
    if (!ok_[r]) continue;
    const float* wr = embWf + (size_t)wt_[r]*HDIM;
    size_t rb = (size_t)prow_[r]*HDIM;
    #pragma unroll
    for (int nt=0;nt<4;nt++){
      int col = nt*16 + c16;
      float v = sigf(g4[nt][r] + wr[col]) * cc[r][nt];
      if (mode == 2){
        f16x2 o; o.x = hh[r][nt]; o.y = (f16)v;
        accOut[rb + col] = o;
      } else {
        atomAddH2(&accOut[rb + col], hh[r][nt], (f16)v);
      }
    }
  }
}

// ================= root =================
__global__ __launch_bounds__(256) void rootred_kernel(
    const f16x2* __restrict__ HFin, float* __restrict__ rootacc)
{
  int t = blockIdx.x*blockDim.x + threadIdx.x;
  int m = t & 63;
  int j0 = t >> 6;
  int jstep = (gridDim.x*blockDim.x) >> 6;
  float af=0.f, ah=0.f;
  for (int j=j0; j<PER; j+=jstep){
    f16x2 v = HFin[(size_t)j*HDIM + m];
    ah += (float)v.x;
    af += (float)v.y;
  }
  __shared__ float red[256];
  red[threadIdx.x]=af; __syncthreads();
  if (threadIdx.x < 64) atomicAdd(&rootacc[m],    red[m]+red[64+m]+red[128+m]+red[192+m]);
  __syncthreads();
  red[threadIdx.x]=ah; __syncthreads();
  if (threadIdx.x < 64) atomicAdd(&rootacc[64+m], red[m]+red[64+m]+red[128+m]+red[192+m]);
}

__global__ void rootnode_kernel(
    const int* __restrict__ tok, const float* __restrict__ emb,
    const float* __restrict__ Wiou, const float* __restrict__ biou, const float* __restrict__ Uiou,
    const float* __restrict__ rootacc, float* __restrict__ out)
{
  int m = threadIdx.x;
  if (m >= HDIM) return;
  int t = tok[0];
  float ai=biou[m], ao=biou[HDIM+m], au=biou[2*HDIM+m];
  for (int e=0;e<EDIM;e++){
    float xe = emb[(size_t)t*EDIM+e];
    ai += Wiou[(size_t)m*EDIM+e]*xe;
    ao += Wiou[(size_t)(HDIM+m)*EDIM+e]*xe;
    au += Wiou[(size_t)(2*HDIM+m)*EDIM+e]*xe;
  }
  for (int k=0;k<HDIM;k++){
    float hv = rootacc[64+k];
    ai += Uiou[(size_t)m*HDIM+k]*hv;
    ao += Uiou[(size_t)(HDIM+m)*HDIM+k]*hv;
    au += Uiou[(size_t)(2*HDIM+m)*HDIM+k]*hv;
  }
  float c = sigf(ai)*tanh_f(au) + rootacc[m];
  out[m] = sigf(ao)*tanh_f(c);
}

// ================= launch =================
static inline char* alignup(char* p){
  uintptr_t u = (uintptr_t)p;
  u = (u + 255) & ~(uintptr_t)255;
  return (char*)u;
}

extern "C" void kernel_launch(void* const* d_in, const int* in_sizes, int n_in,
                              void* d_out, int out_size, void* d_ws, size_t ws_size,
                              hipStream_t stream)
{
  const int*   tok    = (const int*)d_in[0];
  const int*   parent = (const int*)d_in[1];
  const float* emb    = (const float*)d_in[4];
  const float* Wiou   = (const float*)d_in[5];
  const float* biou   = (const float*)d_in[6];
  const float* Uiou   = (const float*)d_in[7];
  const float* Wf     = (const float*)d_in[8];
  const float* bf     = (const float*)d_in[9];
  const float* Uf     = (const float*)d_in[10];
  float* out = (float*)d_out;

  char* w = (char*)d_ws;
  size_t BUF = (size_t)PER*HDIM*sizeof(f16x2);     // 38.3 MB
  f16x2* bufA    = (f16x2*)w;  w = alignup(w + BUF);
  f16x2* bufB    = (f16x2*)w;  w = alignup(w + BUF);
  float* embWiou = (float*)w;  w = alignup(w + 1024*NIOU*sizeof(float));
  float* embWf   = (float*)w;  w = alignup(w + 1024*HDIM*sizeof(float));
  float* rootacc = (float*)w;  w = alignup(w + 128*sizeof(float));
  f16*   Ufpack  = (f16*)w;    w = alignup(w + 2*4*64*8*sizeof(f16));
  f16*   Biopack = (f16*)w;    w = alignup(w + 2*12*64*8*sizeof(f16));

  const int NB = (PER + 63)/64;   // 2341 blocks of 256 threads (4 waves x 16 nodes)

  (void)hipMemsetAsync(rootacc, 0, 128*sizeof(float), stream);
  (void)hipMemsetAsync(bufA, 0, BUF, stream);
  (void)hipMemsetAsync(bufB, 0, BUF, stream);
  tablepack_kernel<<<1025, 256, 0, stream>>>(emb, Wiou, biou, Wf, bf, Uf, Uiou,
                                             embWiou, embWf, Ufpack, Biopack);

  // level d kernel: nodes at poff=1+(d-1)*PER; parents at ppoff=1+(d-2)*PER
  // d=7 (leaves): mode 0 -> atomic into bufA (accum for level 6)
  // d=6..2:       mode 1 -> read own accum, atomic into other buf
  //               zin=1 for d>=3: zero accIn in-kernel (it is the atomic
  //               target at the next level) instead of a memset dispatch.
  // d=1:          mode 2 -> read own accum, plain write {h,fc} (for rootred)
  f16x2* accIn  = nullptr;
  f16x2* accOut = bufA;
  level_kernel<<<NB, 256, 0, stream>>>(tok, parent, embWiou, embWf, Biopack, Ufpack,
                                       nullptr, bufA, 1 + 6*PER, 1 + 5*PER, 0, 0);
  accIn = bufA; accOut = bufB;
  for (int d=6; d>=2; --d){
    level_kernel<<<NB, 256, 0, stream>>>(tok, parent, embWiou, embWf, Biopack, Ufpack,
                                         accIn, accOut, 1 + (d-1)*PER, 1 + (d-2)*PER, 1,
                                         (d >= 3) ? 1 : 0);
    f16x2* t2 = accIn; accIn = accOut; accOut = t2;
  }
  // d=1: plain contiguous write into accOut (full overwrite, no zero needed)
  level_kernel<<<NB, 256, 0, stream>>>(tok, parent, embWiou, embWf, Biopack, Ufpack,
                                       accIn, accOut, 1, 0, 2, 0);

  rootred_kernel<<<256, 256, 0, stream>>>(accOut, rootacc);
  rootnode_kernel<<<1, 64, 0, stream>>>(tok, emb, Wiou, biou, Uiou, rootacc, out);
}